// Round 5
// baseline (769.218 us; speedup 1.0000x reference)
//
#include <hip/hip_runtime.h>
#include <hip/hip_bf16.h>
#include <stdint.h>

// ---------------------------------------------------------------------------
// LSTM2 fused: 3 stacked single-step LSTM cells (h0=c0=0 => f-gate dead) +
// fc1, all in ONE kernel (row-local chain: xt[r]->h1[r]->h2[r]->h3[r]->y[r]).
// h stays in LDS between layers (XOR-swizzled, conflict-free); W streams
// from L2 straight into registers (no K-loop barriers). fc2 is a tiny
// follow-up kernel. ALL I/O f32; internals bf16 MFMA.
// ---------------------------------------------------------------------------

typedef __attribute__((ext_vector_type(8))) short bf16x8;
typedef __attribute__((ext_vector_type(4))) float f32x4;

#define M_ROWS 172032
#define BATCH  8192

__device__ __forceinline__ float bf2f(unsigned short u) {
    union { unsigned int i; float f; } v; v.i = ((unsigned int)u) << 16; return v.f;
}
__device__ __forceinline__ unsigned short f2bf(float f) {
    union { float f; unsigned int i; } v; v.f = f;
    unsigned int r = v.i + 0x7fffu + ((v.i >> 16) & 1u);
    return (unsigned short)(r >> 16);
}
__device__ __forceinline__ float sigmoidf_(float x) {
    return __builtin_amdgcn_rcpf(1.0f + __expf(-x));   // inf-safe
}
__device__ __forceinline__ float tanhf_(float x) {
    x = fminf(fmaxf(x, -20.0f), 20.0f);
    float e = __expf(-2.0f * x);
    return (1.0f - e) * __builtin_amdgcn_rcpf(1.0f + e);
}
// async global->LDS DMA: 16B/lane, dest = wave-uniform base + lane*16
__device__ __forceinline__ void g2l16(const unsigned short* g, unsigned short* l) {
    __builtin_amdgcn_global_load_lds(
        (const __attribute__((address_space(1))) unsigned int*)g,
        (__attribute__((address_space(3))) unsigned int*)l, 16, 0, 0);
}

// ---------------------------------------------------------------------------
// f32 -> bf16 bulk convert (weights), n4 = n/4
// ---------------------------------------------------------------------------
__global__ __launch_bounds__(256) void k_convert(
    const float* __restrict__ src, unsigned short* __restrict__ dst, int n4)
{
    int i = blockIdx.x * 256 + threadIdx.x;
    if (i < n4) {
        float4 v = ((const float4*)src)[i];
        ushort4 o;
        o.x = f2bf(v.x); o.y = f2bf(v.y); o.z = f2bf(v.z); o.w = f2bf(v.w);
        ((ushort4*)dst)[i] = o;
    }
}

// ---------------------------------------------------------------------------
// x (Bc, 128, 21) f32 -> xt (Bc*21, 128) bf16 row-major. One block per b.
// ---------------------------------------------------------------------------
__global__ __launch_bounds__(256) void k_transpose(
    const float* __restrict__ x, unsigned short* __restrict__ xt)
{
    __shared__ unsigned short tile[128 * 22];
    const int b = blockIdx.x, tid = threadIdx.x;
    const float* xb = x + (size_t)b * 2688;
    for (int idx = tid; idx < 2688; idx += 256) {
        int i = idx / 21, t = idx - i * 21;
        tile[i * 22 + t] = f2bf(xb[idx]);
    }
    __syncthreads();
    unsigned short* xtb = xt + (size_t)b * 2688;
    for (int idx = tid; idx < 2688; idx += 256) {
        int t = idx >> 7, i = idx & 127;
        xtb[t * 128 + i] = tile[i * 22 + t];
    }
}

// ---------------------------------------------------------------------------
// One LSTM layer inside the fused kernel.
// hin:  LDS [64][K] bf16, granule-swizzled (phys granule = g ^ (row&7))
// hout: LDS [64][HG] bf16, same swizzle
// W: global bf16 (4*HG, K) row-major, gate order i,f,g,o (f skipped).
// 4 waves = 4 col-waves x full 64 rows; wave tile 64r x 32c x 3 gates
// (m=4, n=2). Per 32-k step: 4 LDS A-frag reads + 6 global W-frag reads,
// 24 MFMA. No barriers inside.
// ---------------------------------------------------------------------------
template<int K, int HG>
__device__ __forceinline__ void gemm_layer(
    const unsigned short* hin, unsigned short* hout,
    const unsigned short* __restrict__ W,
    const float* __restrict__ bih, const float* __restrict__ bhh,
    int wave, int lane)
{
    const int quad = lane >> 4;
    const int rsel = lane & 15;
    const int r7   = rsel & 7;

#pragma unroll
    for (int pass = 0; pass < HG / 128; ++pass) {
        const int c0 = pass * 128 + wave * 32;

        float bias[3][2];
#pragma unroll
        for (int g = 0; g < 3; ++g) {
            int gb = (g == 0) ? 0 : (g + 1) * HG;   // i->0, g->2HG, o->3HG
#pragma unroll
            for (int n = 0; n < 2; ++n) {
                int idx = gb + c0 + n * 16 + rsel;
                bias[g][n] = bih[idx] + bhh[idx];
            }
        }

        f32x4 acc[3][4][2];
#pragma unroll
        for (int g = 0; g < 3; ++g)
#pragma unroll
            for (int m = 0; m < 4; ++m)
#pragma unroll
                for (int n = 0; n < 2; ++n)
                    acc[g][m][n] = (f32x4){0.f, 0.f, 0.f, 0.f};

#pragma unroll
        for (int ks = 0; ks < K / 32; ++ks) {
            bf16x8 af[4];
            const int gsw = (ks * 4 + quad) ^ r7;   // swizzled granule
#pragma unroll
            for (int m = 0; m < 4; ++m)
                af[m] = *(const bf16x8*)&hin[(m * 16 + rsel) * K + gsw * 8];
            bf16x8 bfr[3][2];
#pragma unroll
            for (int g = 0; g < 3; ++g) {
                int gb = (g == 0) ? 0 : (g + 1) * HG;
#pragma unroll
                for (int n = 0; n < 2; ++n) {
                    int col = gb + c0 + n * 16 + rsel;
                    bfr[g][n] = *(const bf16x8*)&W[(size_t)col * K + ks * 32 + quad * 8];
                }
            }
#pragma unroll
            for (int g = 0; g < 3; ++g)
#pragma unroll
                for (int m = 0; m < 4; ++m)
#pragma unroll
                    for (int n = 0; n < 2; ++n)
                        acc[g][m][n] = __builtin_amdgcn_mfma_f32_16x16x32_bf16(
                            af[m], bfr[g][n], acc[g][m][n], 0, 0, 0);
        }

        // epilogue: C/D layout col = lane&15, row = quad*4 + reg (+ m*16)
#pragma unroll
        for (int m = 0; m < 4; ++m)
#pragma unroll
            for (int n = 0; n < 2; ++n) {
                f32x4 vi = acc[0][m][n], vg = acc[1][m][n], vo = acc[2][m][n];
                int col = c0 + n * 16 + rsel;
#pragma unroll
                for (int r = 0; r < 4; ++r) {
                    int row = m * 16 + quad * 4 + r;
                    float cv = sigmoidf_(vi[r] + bias[0][n]) * tanhf_(vg[r] + bias[1][n]);
                    float h  = sigmoidf_(vo[r] + bias[2][n]) * tanhf_(cv);
                    int gcs = (col >> 3) ^ (row & 7);
                    hout[row * HG + gcs * 8 + (col & 7)] = f2bf(h);
                }
            }
    }
}

// ---------------------------------------------------------------------------
// Fused L1+L2+L3+fc1. Block = 64 M-rows, 256 threads (4 waves).
// ---------------------------------------------------------------------------
__global__ __launch_bounds__(256, 2) void k_fused(
    const unsigned short* __restrict__ xt,   // (R,128) bf16
    const unsigned short* __restrict__ W1,
    const unsigned short* __restrict__ W2,
    const unsigned short* __restrict__ W3,
    const float* __restrict__ b1i, const float* __restrict__ b1h,
    const float* __restrict__ b2i, const float* __restrict__ b2h,
    const float* __restrict__ b3i, const float* __restrict__ b3h,
    const float* __restrict__ fc1w, const float* __restrict__ fc1b,
    float* __restrict__ y)                   // (R,) f32
{
    __shared__ __align__(16) unsigned short bufA[64 * 256]; // xt(64x128) / h2(64x256)
    __shared__ __align__(16) unsigned short bufB[64 * 256]; // h1(64x256) / h3(64x128)
    __shared__ float ypart[4][64];

    const int tid  = threadIdx.x;
    const int wave = tid >> 6;
    const int lane = tid & 63;
    const int r0   = blockIdx.x * 64;

    // ---- DMA xt block (64 rows x 128 k) into bufA, swizzled ----
    // DMA d covers rows d*4..d*4+3; lane l -> row d*4+(l>>4), granule pos l&15;
    // source granule = pos ^ (row&7)  (self-inverse swizzle)
#pragma unroll
    for (int i = 0; i < 4; ++i) {
        int d   = wave * 4 + i;
        int row = d * 4 + (lane >> 4);
        int g   = (lane & 15) ^ (row & 7);
        g2l16(xt + (size_t)(r0 + row) * 128 + g * 8, &bufA[d * 512]);
    }
    __syncthreads();

    gemm_layer<128, 256>(bufA, bufB, W1, b1i, b1h, wave, lane);
    __syncthreads();
    gemm_layer<256, 256>(bufB, bufA, W2, b2i, b2h, wave, lane);
    __syncthreads();
    gemm_layer<256, 128>(bufA, bufB, W3, b3i, b3h, wave, lane);
    __syncthreads();

    // ---- fc1: y[row] = fc1b + sum_c fc1w[c] * h3[row][c] ----
    {
        int row = tid & 63, part = tid >> 6;   // 4 parts x 32 cols
        float s = 0.f;
#pragma unroll 8
        for (int i = 0; i < 32; ++i) {
            int c = part * 32 + i;
            int gcs = (c >> 3) ^ (row & 7);
            s += fc1w[c] * bf2f(bufB[row * 128 + gcs * 8 + (c & 7)]);
        }
        ypart[part][row] = s;
        __syncthreads();
        if (tid < 64)
            y[r0 + tid] = fc1b[0] + ypart[0][tid] + ypart[1][tid]
                        + ypart[2][tid] + ypart[3][tid];
    }
}

// ---------------------------------------------------------------------------
// fc2: out[b,tp] = fc2b[tp] + sum_t y[b,t] * fc2w[tp,t].  8 b per block.
// ---------------------------------------------------------------------------
__global__ __launch_bounds__(256) void k_fc2(
    const float* __restrict__ y, const float* __restrict__ fc2w,
    const float* __restrict__ fc2b, float* __restrict__ out)
{
    __shared__ float yl[168], f2l[441], f2bl[21];
    const int tid = threadIdx.x;
    const int b0 = blockIdx.x * 8;
    for (int i = tid; i < 441; i += 256) f2l[i] = fc2w[i];
    if (tid < 21) f2bl[tid] = fc2b[tid];
    if (tid < 168) yl[tid] = y[(size_t)b0 * 21 + tid];
    __syncthreads();
    if (tid < 168) {
        int bloc = tid / 21, tp = tid - bloc * 21;
        float s = f2bl[tp];
#pragma unroll
        for (int t = 0; t < 21; ++t)
            s += yl[bloc * 21 + t] * f2l[tp * 21 + t];
        out[(size_t)(b0 + bloc) * 21 + tp] = s;
    }
}

// ---------------------------------------------------------------------------
extern "C" void kernel_launch(void* const* d_in, const int* in_sizes, int n_in,
                              void* d_out, int out_size, void* d_ws, size_t ws_size,
                              hipStream_t stream)
{
    const float* x    = (const float*)d_in[0];
    const float* W1   = (const float*)d_in[1];
    const float* b1i  = (const float*)d_in[2];
    const float* b1h  = (const float*)d_in[3];
    const float* W2   = (const float*)d_in[4];
    const float* b2i  = (const float*)d_in[5];
    const float* b2h  = (const float*)d_in[6];
    const float* W3   = (const float*)d_in[7];
    const float* b3i  = (const float*)d_in[8];
    const float* b3h  = (const float*)d_in[9];
    const float* fc1w = (const float*)d_in[10];
    const float* fc1b = (const float*)d_in[11];
    const float* fc2w = (const float*)d_in[12];
    const float* fc2b = (const float*)d_in[13];
    float* out = (float*)d_out;

    // ws: [Wc1 1024x128][Wc2 1024x256][Wc3 512x256] bf16 (1 MB),
    // then per-chunk: xt (R x 128 bf16, 256 B/row) + y (R f32, 4 B/row).
    unsigned short* Wc1 = (unsigned short*)d_ws;
    unsigned short* Wc2 = Wc1 + 131072;
    unsigned short* Wc3 = Wc2 + 262144;
    unsigned short* buf = Wc3 + 131072;          // 1 MB in

    int C = 1;
    while (C < 64 && 1048576 + (size_t)(M_ROWS / C) * 260 > ws_size) C <<= 1;
    const int R  = M_ROWS / C;   // rows per chunk (multiple of 2688; 2688=42*64)
    const int Bc = BATCH / C;

    unsigned short* xt = buf;
    float* y = (float*)(xt + (size_t)R * 128);

    k_convert<<<128, 256, 0, stream>>>(W1, Wc1, 32768);
    k_convert<<<256, 256, 0, stream>>>(W2, Wc2, 65536);
    k_convert<<<128, 256, 0, stream>>>(W3, Wc3, 32768);

    for (int c = 0; c < C; ++c) {
        const float* xc = x + (size_t)c * Bc * 2688;
        k_transpose<<<Bc, 256, 0, stream>>>(xc, xt);
        k_fused<<<R / 64, 256, 0, stream>>>(xt, Wc1, Wc2, Wc3,
                                            b1i, b1h, b2i, b2h, b3i, b3h,
                                            fc1w, fc1b, y);
        k_fc2<<<Bc / 8, 256, 0, stream>>>(y, fc2w, fc2b,
                                          out + (size_t)c * Bc * 21);
    }
}